// Round 2
// baseline (826.216 us; speedup 1.0000x reference)
//
#include <hip/hip_runtime.h>
#include <math.h>

typedef __attribute__((ext_vector_type(2))) float f32x2;
typedef __attribute__((ext_vector_type(4))) float f32x4;
typedef __attribute__((ext_vector_type(4))) unsigned int u32x4;
typedef __attribute__((ext_vector_type(8))) unsigned short u16x8;
typedef __attribute__((ext_vector_type(8))) __bf16 bf16x8;
typedef unsigned short ushort_t;

#define H_DIM 2048
#define T_TOK 2048
#define NEXP 16
#define I_DIM 1408
#define I2_DIM 2816
#define IS_DIM 5632
#define MAXROWS 6144

static __device__ __forceinline__ unsigned short f2bf(float f){
  union { float f; unsigned u; } v; v.f = f;
  unsigned r = v.u + 0x7FFFu + ((v.u >> 16) & 1u);
  return (unsigned short)(r >> 16);
}
static __device__ __forceinline__ float bf2f(unsigned short h){
  union { unsigned u; float f; } v; v.u = ((unsigned)h) << 16;
  return v.f;
}
static __device__ __forceinline__ float silu_f(float x){ return x / (1.f + __expf(-x)); }

// Swizzled LDS element offset for a [128 rows][64 k] bf16 tile.
// 16B slot index XORed with (row>>1)&7: write side (transposed B: row=n pair-shared,
// linear A: 8 slots per row) and fragment-read side both spread evenly over bank quads.
static __device__ __forceinline__ int swz(int row, int slot){
  return row * 64 + ((slot ^ ((row >> 1) & 7)) << 3);
}

// ---------------- cast x -> bf16 ----------------
__global__ void cast_bf16_k(const float* __restrict__ in, ushort_t* __restrict__ out){
  long i = ((long)blockIdx.x * 256 + threadIdx.x) * 8;
  f32x4 a = *(const f32x4*)&in[i];
  f32x4 b = *(const f32x4*)&in[i + 4];
  union { ushort_t s[8]; u32x4 v; } pk;
  #pragma unroll
  for (int j = 0; j < 4; j++){ pk.s[j] = f2bf(a[j]); pk.s[j+4] = f2bf(b[j]); }
  *(u32x4*)&out[i] = pk.v;
}

// ---------------- router: logits, top-2 renorm, shared gate, compaction ----------------
__global__ void router_k(const float* __restrict__ x, const float* __restrict__ rw,
                         const float* __restrict__ sgw, float* __restrict__ logits,
                         int* __restrict__ counts, int* __restrict__ lists,
                         float* __restrict__ probs, float* __restrict__ sgmul){
  int wid = threadIdx.x >> 6, lane = threadIdx.x & 63;
  int t = blockIdx.x * 4 + wid;
  const float* xr = x + (long)t * H_DIM;
  float acc[17];
  #pragma unroll
  for (int e = 0; e < 17; e++) acc[e] = 0.f;
  for (int h0 = lane * 4; h0 < H_DIM; h0 += 256){
    f32x4 xv = *(const f32x4*)&xr[h0];
    #pragma unroll
    for (int i = 0; i < 4; i++){
      float xs = xv[i];
      const float* wrow = rw + (long)(h0 + i) * NEXP;
      #pragma unroll
      for (int e = 0; e < 16; e++) acc[e] += xs * wrow[e];
      acc[16] += xs * sgw[h0 + i];
    }
  }
  #pragma unroll
  for (int e = 0; e < 17; e++)
    for (int off = 32; off >= 1; off >>= 1)
      acc[e] += __shfl_xor(acc[e], off);
  if (lane == 0){
    float* lo = logits + (long)t * NEXP;
    #pragma unroll
    for (int e = 0; e < 16; e++) lo[e] = acc[e];
    int e0 = 0;
    #pragma unroll
    for (int e = 1; e < 16; e++) if (acc[e] > acc[e0]) e0 = e;
    int e1 = (e0 == 0) ? 1 : 0;
    #pragma unroll
    for (int e = 0; e < 16; e++) if (e != e0 && acc[e] > acc[e1]) e1 = e;
    float d = acc[e1] - acc[e0];       // <= 0
    float ed = __expf(d);
    float p0 = 1.f / (1.f + ed);
    float p1 = ed / (1.f + ed);
    int pos0 = atomicAdd(&counts[e0], 1);
    lists[e0 * T_TOK + pos0] = t; probs[e0 * T_TOK + pos0] = p0;
    int pos1 = atomicAdd(&counts[e1], 1);
    lists[e1 * T_TOK + pos1] = t; probs[e1 * T_TOK + pos1] = p1;
    sgmul[t] = 1.f / (1.f + __expf(-acc[16]));
  }
}

// ---------------- padded prefix bases ----------------
__global__ void bases_k(const int* __restrict__ counts, int* __restrict__ bases){
  if (threadIdx.x == 0){
    int r = 0;
    for (int e = 0; e < NEXP; e++){ bases[e] = r; r += (counts[e] + 127) & ~127; }
  }
}

// ---------------- SwiGLU elementwise ----------------
__global__ void swiglu_expert_k(const ushort_t* __restrict__ gu, ushort_t* __restrict__ hid){
  long qd = (long)blockIdx.x * 256 + threadIdx.x;
  long r = qd / (I_DIM / 8); int ic = (int)(qd % (I_DIM / 8)) * 8;
  const ushort_t* g = gu + r * I2_DIM + ic;
  u16x8 gv = *(const u16x8*)g;
  u16x8 uv = *(const u16x8*)(g + I_DIM);
  u16x8 ov;
  #pragma unroll
  for (int i = 0; i < 8; i++)
    ov[i] = f2bf(bf2f(uv[i]) * silu_f(bf2f(gv[i])));
  *(u16x8*)&hid[r * I_DIM + ic] = ov;
}

__global__ void swiglu_flat_k(ushort_t* __restrict__ sg, const ushort_t* __restrict__ si){
  long i = ((long)blockIdx.x * 256 + threadIdx.x) * 8;
  u16x8 g = *(const u16x8*)&sg[i];
  u16x8 s = *(const u16x8*)&si[i];
  u16x8 o;
  #pragma unroll
  for (int j = 0; j < 8; j++)
    o[j] = f2bf(bf2f(s[j]) * silu_f(bf2f(g[j])));
  *(u16x8*)&sg[i] = o;
}

// ---------------- GEMM: A[M][K] bf16 (opt gathered), B[K][N] fp32 (fused cast+transpose) --------
// MODE 0: raw bf16 store to Cb.  MODE 1: expert gate_up, gather A rows via lists, masked store.
// MODE 2: expert out, atomicAdd p*val into outp scattered by token.  MODE 3: store svec[m]*val.
template<int MODE>
__global__ __launch_bounds__(256, 2)
void gemm_k(const ushort_t* __restrict__ A, const float* __restrict__ Bf,
            ushort_t* __restrict__ Cb,
            int K, int lda, int ldb, int ldc, int mb,
            const int* __restrict__ counts, const int* __restrict__ bases,
            const int* __restrict__ lists, const float* __restrict__ probs,
            const float* __restrict__ svec, float* __restrict__ outp,
            long bstride){
  int z = blockIdx.z;
  int cnt = T_TOK;
  const ushort_t* Ab = A;
  const float* Bb = Bf;
  long rbase = 0;
  if constexpr (MODE == 1){ cnt = counts[z]; rbase = bases[z]; Bb += (long)z * bstride; }
  if constexpr (MODE == 2){ cnt = counts[z]; Ab += (long)bases[z] * lda; Bb += (long)z * bstride; }

  // bijective XCD-chunked swizzle (m204), m-fastest decode: contiguous chunk per XCD
  // shares B panels in that XCD's L2.
  int nwg = gridDim.x;
  int wgo = blockIdx.x;
  int q = nwg >> 3, r = nwg & 7;
  int xcd = wgo & 7, idx = wgo >> 3;
  int wg = (xcd < r ? xcd * (q + 1) : r * (q + 1) + (xcd - r) * q) + idx;
  int mblk = wg % mb, nblk = wg / mb;
  int m0 = mblk * 128;
  if (m0 >= cnt) return;
  int n0 = nblk * 128;

  __shared__ ushort_t As[128 * 64];
  __shared__ ushort_t Bs[128 * 64];

  int tid = threadIdx.x;
  int lane = tid & 63;
  int wv = tid >> 6;
  int wr = wv >> 1, wc = wv & 1;

  // ---- A staging: 4 items (m,slot), bf16 b128 loads ----
  const ushort_t* aptr[4];
  int am[4], aslot[4];
  #pragma unroll
  for (int qq = 0; qq < 4; qq++){
    int it = tid + qq * 256;
    int m = it >> 3, slot = it & 7;
    am[qq] = m; aslot[qq] = slot;
    int row;
    if constexpr (MODE == 1){
      int j = m0 + m; if (j >= cnt) j = cnt - 1;
      row = lists[z * T_TOK + j];
    } else {
      row = m0 + m;
    }
    aptr[qq] = Ab + (long)row * lda + slot * 8;
  }
  // ---- B staging: lane owns column pair (2p,2p+1), wave owns slot pair (sp, sp+4) ----
  int p = lane;
  int sp = wv;
  const float* bb0 = Bb + (long)(sp * 8) * ldb + n0 + 2 * p;
  const float* bb1 = bb0 + (long)32 * ldb;

  u32x4 ar[4];
  f32x2 br0[8], br1[8];
  #pragma unroll
  for (int qq = 0; qq < 4; qq++) ar[qq] = *(const u32x4*)(aptr[qq]);
  #pragma unroll
  for (int i = 0; i < 8; i++){
    br0[i] = *(const f32x2*)(bb0 + (long)i * ldb);
    br1[i] = *(const f32x2*)(bb1 + (long)i * ldb);
  }

  f32x4 zero = {0.f, 0.f, 0.f, 0.f};
  f32x4 acc[4][4];
  #pragma unroll
  for (int i = 0; i < 4; i++)
    #pragma unroll
    for (int j = 0; j < 4; j++) acc[i][j] = zero;

  int nsteps = K >> 6;
  for (int s = 0; s < nsteps; s++){
    __syncthreads();
    #pragma unroll
    for (int qq = 0; qq < 4; qq++)
      *(u32x4*)&As[swz(am[qq], aslot[qq])] = ar[qq];
    {
      bf16x8 c0, c1, d0, d1;
      #pragma unroll
      for (int i = 0; i < 8; i++){
        c0[i] = (__bf16)br0[i][0];
        c1[i] = (__bf16)br0[i][1];
        d0[i] = (__bf16)br1[i][0];
        d1[i] = (__bf16)br1[i][1];
      }
      *(bf16x8*)&Bs[swz(2*p,     sp)]     = c0;
      *(bf16x8*)&Bs[swz(2*p + 1, sp)]     = c1;
      *(bf16x8*)&Bs[swz(2*p,     sp + 4)] = d0;
      *(bf16x8*)&Bs[swz(2*p + 1, sp + 4)] = d1;
    }
    __syncthreads();
    if (s + 1 < nsteps){
      int kt = (s + 1) * 64;
      #pragma unroll
      for (int qq = 0; qq < 4; qq++) ar[qq] = *(const u32x4*)(aptr[qq] + kt);
      const float* nb0 = bb0 + (long)kt * ldb;
      const float* nb1 = bb1 + (long)kt * ldb;
      #pragma unroll
      for (int i = 0; i < 8; i++){
        br0[i] = *(const f32x2*)(nb0 + (long)i * ldb);
        br1[i] = *(const f32x2*)(nb1 + (long)i * ldb);
      }
    }
    #pragma unroll
    for (int kk = 0; kk < 2; kk++){
      bf16x8 af[4], bg[4];
      #pragma unroll
      for (int f = 0; f < 4; f++){
        af[f] = *(const bf16x8*)&As[swz(wr*64 + f*16 + (lane & 15), kk*4 + (lane >> 4))];
        bg[f] = *(const bf16x8*)&Bs[swz(wc*64 + f*16 + (lane & 15), kk*4 + (lane >> 4))];
      }
      #pragma unroll
      for (int fm = 0; fm < 4; fm++)
        #pragma unroll
        for (int fn = 0; fn < 4; fn++)
          acc[fm][fn] = __builtin_amdgcn_mfma_f32_16x16x32_bf16(af[fm], bg[fn], acc[fm][fn], 0, 0, 0);
    }
  }

  int colb = n0 + wc * 64 + (lane & 15);
  int rowb = m0 + wr * 64 + (lane >> 4) * 4;
  #pragma unroll
  for (int fm = 0; fm < 4; fm++){
    #pragma unroll
    for (int fn = 0; fn < 4; fn++){
      f32x4 v = acc[fm][fn];
      int col = colb + fn * 16;
      #pragma unroll
      for (int rr = 0; rr < 4; rr++){
        int m = rowb + fm * 16 + rr;
        if constexpr (MODE == 0){
          Cb[(long)m * ldc + col] = f2bf(v[rr]);
        } else if constexpr (MODE == 1){
          if (m < cnt) Cb[(rbase + m) * (long)ldc + col] = f2bf(v[rr]);
        } else if constexpr (MODE == 2){
          if (m < cnt){
            int tok = lists[z * T_TOK + m];
            float pp = probs[z * T_TOK + m];
            atomicAdd(outp + (long)tok * ldc + col, pp * v[rr]);
          }
        } else {
          outp[(long)m * ldc + col] = svec[m] * v[rr];
        }
      }
    }
  }
}

extern "C" void kernel_launch(void* const* d_in, const int* in_sizes, int n_in,
                              void* d_out, int out_size, void* d_ws, size_t ws_size,
                              hipStream_t stream){
  const float* x    = (const float*)d_in[0];
  const float* rw   = (const float*)d_in[1];
  const float* wgu  = (const float*)d_in[2];
  const float* wout = (const float*)d_in[3];
  const float* wsg  = (const float*)d_in[4];
  const float* wsi  = (const float*)d_in[5];
  const float* wso  = (const float*)d_in[6];
  const float* sgw  = (const float*)d_in[7];

  float* out = (float*)d_out;
  float* logits = out + (size_t)T_TOK * H_DIM;

  char* w = (char*)d_ws;
  auto alloc = [&](size_t b){ char* p = w; w += (b + 255) & ~(size_t)255; return p; };
  ushort_t* xb  = (ushort_t*)alloc((size_t)T_TOK * H_DIM * 2);
  ushort_t* sgr = (ushort_t*)alloc((size_t)T_TOK * IS_DIM * 2);
  ushort_t* sir = (ushort_t*)alloc((size_t)T_TOK * IS_DIM * 2);
  ushort_t* gu  = (ushort_t*)alloc((size_t)MAXROWS * I2_DIM * 2);
  ushort_t* hid = (ushort_t*)alloc((size_t)MAXROWS * I_DIM * 2);
  int*   counts = (int*)alloc(64);
  int*   bases  = (int*)alloc(64);
  int*   lists  = (int*)alloc((size_t)NEXP * T_TOK * 4);
  float* probs  = (float*)alloc((size_t)NEXP * T_TOK * 4);
  float* sgmul  = (float*)alloc((size_t)T_TOK * 4);

  hipMemsetAsync(counts, 0, 64, stream);

  cast_bf16_k<<<2048, 256, 0, stream>>>(x, xb);
  router_k<<<512, 256, 0, stream>>>(x, rw, sgw, logits, counts, lists, probs, sgmul);
  bases_k<<<1, 64, 0, stream>>>(counts, bases);

  // shared expert path (MODE 3 initializes out)
  gemm_k<0><<<dim3((IS_DIM/128) * (T_TOK/128), 1, 1), 256, 0, stream>>>(
      xb, wsg, sgr, H_DIM, H_DIM, IS_DIM, IS_DIM, T_TOK/128,
      nullptr, nullptr, nullptr, nullptr, nullptr, nullptr, 0);
  gemm_k<0><<<dim3((IS_DIM/128) * (T_TOK/128), 1, 1), 256, 0, stream>>>(
      xb, wsi, sir, H_DIM, H_DIM, IS_DIM, IS_DIM, T_TOK/128,
      nullptr, nullptr, nullptr, nullptr, nullptr, nullptr, 0);
  swiglu_flat_k<<<(T_TOK * (IS_DIM/8)) / 256, 256, 0, stream>>>(sgr, sir);
  gemm_k<3><<<dim3((H_DIM/128) * (T_TOK/128), 1, 1), 256, 0, stream>>>(
      sgr, wso, nullptr, IS_DIM, IS_DIM, H_DIM, H_DIM, T_TOK/128,
      nullptr, nullptr, nullptr, nullptr, sgmul, out, 0);

  // sparse routed experts (atomic add on top of shared output)
  gemm_k<1><<<dim3((I2_DIM/128) * (T_TOK/128), 1, NEXP), 256, 0, stream>>>(
      xb, wgu, gu, H_DIM, H_DIM, I2_DIM, I2_DIM, T_TOK/128,
      counts, bases, lists, probs, nullptr, nullptr, (long)H_DIM * I2_DIM);
  swiglu_expert_k<<<(MAXROWS * (I_DIM/8)) / 256, 256, 0, stream>>>(gu, hid);
  gemm_k<2><<<dim3((H_DIM/128) * (T_TOK/128), 1, NEXP), 256, 0, stream>>>(
      hid, wout, nullptr, I_DIM, I_DIM, H_DIM, H_DIM, T_TOK/128,
      counts, bases, lists, probs, nullptr, out, (long)I_DIM * H_DIM);

  (void)in_sizes; (void)n_in; (void)out_size; (void)ws_size;
}